// Round 3
// baseline (1943.724 us; speedup 1.0000x reference)
//
#include <hip/hip_runtime.h>
#include <stdint.h>

// SquaredExpModel: GP log-likelihood + posterior mean on MI355X (gfx950).
// R3: gemm1 -> 384-thr blocks (acc 96 AGPR => 2 blocks/CU), B via
// global_load_lds DMA, A dbuf + prefetch; LU chain -> single persistent
// kernel with device-scope atomic grid barrier (25 launches -> 1).

#define NM 10000
#define ND 552
#define NDP 576
#define NKB 313      // k-blocks of 32 (covers 10016, zero-padded)
#define MT64 157     // M tiles of 64 (covers 10048, guarded)
#define SPLITK 3

typedef __attribute__((ext_vector_type(8))) short bf16x8;
typedef __attribute__((ext_vector_type(4))) float f32x4;

__device__ __forceinline__ unsigned short f2bf(float f){
  unsigned u = __float_as_uint(f);
  u += 0x7fffu + ((u >> 16) & 1u);
  return (unsigned short)(u >> 16);
}
__device__ __forceinline__ unsigned int pk2(unsigned short a, unsigned short b){
  return (unsigned int)a | ((unsigned int)b << 16);
}
__device__ __forceinline__ void load_lds16(const void* g, void* s){
  __builtin_amdgcn_global_load_lds(
      (const __attribute__((address_space(1))) unsigned int*)g,
      (__attribute__((address_space(3))) unsigned int*)s, 16, 0, 0);
}

// ---- Build Bt: F^T in [kb][n][32k] bf16, 16B-chunk swizzle q' = (q + (n>>1))&3 ----
__global__ void prep_bt(const float* __restrict__ F, unsigned short* __restrict__ Bt){
  int bid = blockIdx.x;
  int kb = bid % NKB, nb = bid / NKB;
  int t = threadIdx.x;
  int nl = t >> 2, q = t & 3;
  int gn = nb * 64 + nl;
  int k0 = kb * 32 + q * 8;
  float v[8];
  if (gn < ND && (k0 + 8) <= NM){
    const float* p = F + (size_t)gn * NM + k0;
    float4 a = *(const float4*)p;
    float4 b = *(const float4*)(p + 4);
    v[0]=a.x; v[1]=a.y; v[2]=a.z; v[3]=a.w; v[4]=b.x; v[5]=b.y; v[6]=b.z; v[7]=b.w;
  } else {
    #pragma unroll
    for (int i = 0; i < 8; ++i) v[i] = 0.f;
  }
  unsigned short u[8];
  #pragma unroll
  for (int i = 0; i < 8; ++i) u[i] = f2bf(v[i]);
  size_t cidx = ((size_t)kb * NDP + gn) * 4 + ((q + (gn >> 1)) & 3);
  uint4 w;
  w.x = pk2(u[0],u[1]); w.y = pk2(u[2],u[3]); w.z = pk2(u[4],u[5]); w.w = pk2(u[6],u[7]);
  *(uint4*)(Bt + cidx * 8) = w;
}

// ---- r = d_obs - m0 * rowsum(F); rows >= ND get 0 ----
__global__ void rvec(const float* __restrict__ F, const float* __restrict__ dobs,
                     const float* __restrict__ m0p, float* __restrict__ r){
  __shared__ float red[256];
  int i = blockIdx.x;
  int t = threadIdx.x;
  float s = 0.f;
  if (i < ND){
    for (int k = t; k < NM; k += 256) s += F[(size_t)i * NM + k];
  }
  red[t] = s;
  __syncthreads();
  if (t < 64){
    float v = red[t] + red[t+64] + red[t+128] + red[t+192];
    #pragma unroll
    for (int off = 32; off; off >>= 1) v += __shfl_down(v, off);
    if (t == 0){
      if (i < ND) r[i] = dobs[i] - m0p[0] * v;
      else        r[i] = 0.f;
    }
  }
}

// ---- GEMM1: P[m][n] += sum_k sigma^2*exp(ce*D[m][k]) * F[n][k]  (bf16 MFMA) ----
// 384 thr = 6 waves (1M x 6N); wave tile 64x96 (acc 96); block tile 64x576.
// A dbuf LDS (fused exp), B single LDS via global_load_lds DMA. splitK=3.
__global__ __launch_bounds__(384, 3) void gemm1(
    const float* __restrict__ dist, const unsigned short* __restrict__ Bt,
    float* __restrict__ P, const float* __restrict__ lsp, const float* __restrict__ sgp){
  __shared__ unsigned short Alds[2][64 * 40];   // 2 x 5120 B
  __shared__ unsigned short Blds[NDP * 32];     // 36864 B
  int bid = blockIdx.x;
  int mtile = bid % MT64, kc = bid / MT64;
  int kb0 = (kc == 0) ? 0 : (105 + 104 * (kc - 1));
  int kbe = kb0 + ((kc == 0) ? 105 : 104);
  int m0 = mtile * 64;
  float ls = lsp[0], sg = sgp[0];
  float ce = -0.72134752044f / (ls * ls);  // -(log2 e)/(2 l^2)
  float s2 = sg * sg;
  int t = threadIdx.x, lane = t & 63, w = t >> 6;
  int c16 = lane & 15, q2 = lane >> 4;
  int rr = t >> 2, qa = t & 3;     // A-staging role (threads 0..255)

  f32x4 acc[4][6];
  #pragma unroll
  for (int a = 0; a < 4; ++a)
    #pragma unroll
    for (int b = 0; b < 6; ++b) acc[a][b] = (f32x4){0.f, 0.f, 0.f, 0.f};

  // prologue: stage A(kb0) into buf 0, start B(kb0) DMA
  if (t < 256){
    int gm = m0 + rr;
    int k0 = kb0 * 32 + qa * 8;
    float v[8];
    if (gm < NM && (k0 + 8) <= NM){
      const float* p = dist + (size_t)gm * NM + k0;
      float4 x = *(const float4*)p;
      float4 y = *(const float4*)(p + 4);
      v[0]=x.x; v[1]=x.y; v[2]=x.z; v[3]=x.w; v[4]=y.x; v[5]=y.y; v[6]=y.z; v[7]=y.w;
      #pragma unroll
      for (int i = 0; i < 8; ++i) v[i] = s2 * exp2f(v[i] * ce);
    } else {
      #pragma unroll
      for (int i = 0; i < 8; ++i) v[i] = 0.f;
    }
    unsigned short u[8];
    #pragma unroll
    for (int i = 0; i < 8; ++i) u[i] = f2bf(v[i]);
    uint4 wv;
    wv.x = pk2(u[0],u[1]); wv.y = pk2(u[2],u[3]); wv.z = pk2(u[4],u[5]); wv.w = pk2(u[6],u[7]);
    *(uint4*)(&Alds[0][0] + rr * 40 + qa * 8) = wv;
  }
  {
    const unsigned short* src = Bt + (size_t)kb0 * NDP * 32;
    #pragma unroll
    for (int i = 0; i < 6; ++i){
      int idx = t + i * 384;
      load_lds16(src + idx * 8, &Blds[0] + idx * 8);
    }
  }

  int buf = 0;
  for (int kb = kb0; kb < kbe; ++kb){
    __syncthreads();   // A[buf] + B[kb] ready
    // early-issue dist prefetch for kb+1 (latency hides under MFMA)
    float4 pfx, pfy; bool pvalid = false;
    if (t < 256 && kb + 1 < kbe){
      int gm = m0 + rr;
      int k0 = (kb + 1) * 32 + qa * 8;
      pvalid = (gm < NM) && ((k0 + 8) <= NM);
      if (pvalid){
        const float* p = dist + (size_t)gm * NM + k0;
        pfx = *(const float4*)p;
        pfy = *(const float4*)(p + 4);
      }
    }
    // MFMA on current tile
    bf16x8 af[4];
    #pragma unroll
    for (int mt = 0; mt < 4; ++mt)
      af[mt] = *(const bf16x8*)&Alds[buf][(mt * 16 + c16) * 40 + q2 * 8];
    #pragma unroll
    for (int nt = 0; nt < 6; ++nt){
      int n = w * 96 + nt * 16 + c16;
      int cidx = n * 4 + ((q2 + (n >> 1)) & 3);
      bf16x8 bf = *(const bf16x8*)&Blds[cidx * 8];
      #pragma unroll
      for (int mt = 0; mt < 4; ++mt)
        acc[mt][nt] = __builtin_amdgcn_mfma_f32_16x16x32_bf16(af[mt], bf, acc[mt][nt], 0, 0, 0);
    }
    if (kb + 1 < kbe){
      __syncthreads();   // all waves done reading Blds / Alds[buf]
      if (t < 256){
        float v[8];
        if (pvalid){
          v[0]=pfx.x; v[1]=pfx.y; v[2]=pfx.z; v[3]=pfx.w;
          v[4]=pfy.x; v[5]=pfy.y; v[6]=pfy.z; v[7]=pfy.w;
          #pragma unroll
          for (int i = 0; i < 8; ++i) v[i] = s2 * exp2f(v[i] * ce);
        } else {
          #pragma unroll
          for (int i = 0; i < 8; ++i) v[i] = 0.f;
        }
        unsigned short u[8];
        #pragma unroll
        for (int i = 0; i < 8; ++i) u[i] = f2bf(v[i]);
        uint4 wv;
        wv.x = pk2(u[0],u[1]); wv.y = pk2(u[2],u[3]); wv.z = pk2(u[4],u[5]); wv.w = pk2(u[6],u[7]);
        *(uint4*)(&Alds[buf ^ 1][0] + rr * 40 + qa * 8) = wv;
      }
      const unsigned short* src = Bt + (size_t)(kb + 1) * NDP * 32;
      #pragma unroll
      for (int i = 0; i < 6; ++i){
        int idx = t + i * 384;
        load_lds16(src + idx * 8, &Blds[0] + idx * 8);
      }
    }
    buf ^= 1;
  }
  // epilogue: split-K accumulate
  #pragma unroll
  for (int mt = 0; mt < 4; ++mt)
    #pragma unroll
    for (int nt = 0; nt < 6; ++nt)
      #pragma unroll
      for (int e = 0; e < 4; ++e){
        int gm = m0 + mt * 16 + q2 * 4 + e;
        int gn = w * 96 + nt * 16 + c16;
        if (gm < NM) atomicAdd(&P[(size_t)gm * NDP + gn], acc[mt][nt][e]);
      }
}

// ---- Convert P (fp32 [k][n]) -> Pb bf16 swizzled tiles [kb][n][32k] ----
__global__ void conv_p(const float* __restrict__ P, unsigned short* __restrict__ Pb){
  int bid = blockIdx.x;
  int kb = bid % NKB, nb = bid / NKB;
  int t = threadIdx.x;
  int nl = t & 63, q = t >> 6;
  int gn = nb * 64 + nl;
  int k0 = kb * 32 + q * 8;
  unsigned short u[8];
  #pragma unroll
  for (int j = 0; j < 8; ++j){
    int k = k0 + j;
    float v = (k < NM) ? P[(size_t)k * NDP + gn] : 0.f;
    u[j] = f2bf(v);
  }
  size_t cidx = ((size_t)kb * NDP + gn) * 4 + ((q + (gn >> 1)) & 3);
  uint4 w;
  w.x = pk2(u[0],u[1]); w.y = pk2(u[2],u[3]); w.z = pk2(u[4],u[5]); w.w = pk2(u[6],u[7]);
  *(uint4*)(Pb + cidx * 8) = w;
}

// ---- A init (also zeroes the grid-barrier counter for lu_all) ----
__global__ void a_init(const float* __restrict__ dcov, float* __restrict__ A,
                       unsigned* __restrict__ bar){
  int idx = blockIdx.x * 256 + threadIdx.x;
  if (idx == 0) bar[0] = 0u;
  if (idx >= NDP * NDP) return;
  int i = idx / NDP, j = idx % NDP;
  float v;
  if (i < ND && j < ND) v = dcov[i * ND + j];
  else v = (i == j) ? 1.f : 0.f;
  A[idx] = v;
}

// ---- GEMM2: A += F @ P ----
__global__ __launch_bounds__(256) void gemm2(
    const unsigned short* __restrict__ Bt, const unsigned short* __restrict__ Pb,
    float* __restrict__ A){
  __shared__ unsigned short Fa[64 * 32];
  __shared__ unsigned short Pl[64 * 32];
  int bid = blockIdx.x;
  int tile = bid % 81, kc = bid / 81;
  int ti = tile / 9, tj = tile % 9;
  int i0 = ti * 64, j0 = tj * 64;
  int kb0 = (kc == 0) ? 0 : (105 + 104 * (kc - 1));
  int kbe = kb0 + ((kc == 0) ? 105 : 104);
  int t = threadIdx.x, lane = t & 63, w = t >> 6;
  int wm = w & 1, wn = w >> 1;
  int c16 = lane & 15, q2 = lane >> 4;
  f32x4 acc[2][2];
  #pragma unroll
  for (int a = 0; a < 2; ++a)
    #pragma unroll
    for (int b = 0; b < 2; ++b) acc[a][b] = (f32x4){0.f, 0.f, 0.f, 0.f};
  for (int kb = kb0; kb < kbe; ++kb){
    ((uint4*)Fa)[t] = ((const uint4*)Bt)[((size_t)kb * NDP + i0) * 4 + t];
    ((uint4*)Pl)[t] = ((const uint4*)Pb)[((size_t)kb * NDP + j0) * 4 + t];
    __syncthreads();
    bf16x8 af[2], bf[2];
    #pragma unroll
    for (int mt = 0; mt < 2; ++mt){
      int il = wm * 32 + mt * 16 + c16;
      af[mt] = *(const bf16x8*)&Fa[(il * 4 + ((q2 + (il >> 1)) & 3)) * 8];
    }
    #pragma unroll
    for (int nt = 0; nt < 2; ++nt){
      int jl = wn * 32 + nt * 16 + c16;
      bf[nt] = *(const bf16x8*)&Pl[(jl * 4 + ((q2 + (jl >> 1)) & 3)) * 8];
    }
    #pragma unroll
    for (int mt = 0; mt < 2; ++mt)
      #pragma unroll
      for (int nt = 0; nt < 2; ++nt)
        acc[mt][nt] = __builtin_amdgcn_mfma_f32_16x16x32_bf16(af[mt], bf[nt], acc[mt][nt], 0, 0, 0);
    __syncthreads();
  }
  #pragma unroll
  for (int mt = 0; mt < 2; ++mt)
    #pragma unroll
    for (int nt = 0; nt < 2; ++nt)
      #pragma unroll
      for (int e = 0; e < 4; ++e){
        int gi = i0 + wm * 32 + mt * 16 + q2 * 4 + e;
        int gj = j0 + wn * 32 + nt * 16 + c16;
        atomicAdd(&A[(size_t)gi * NDP + gj], acc[mt][nt][e]);
      }
}

// ---- Persistent blocked LU (no pivoting), 81 blocks, atomic grid barrier ----
__device__ __forceinline__ void grid_bar(unsigned* bar, unsigned target){
  __syncthreads();
  if (threadIdx.x == 0){
    __hip_atomic_fetch_add(bar, 1u, __ATOMIC_ACQ_REL, __HIP_MEMORY_SCOPE_AGENT);
    while (__hip_atomic_load(bar, __ATOMIC_ACQUIRE, __HIP_MEMORY_SCOPE_AGENT) < target)
      __builtin_amdgcn_s_sleep(2);
  }
  __syncthreads();
}

__global__ __launch_bounds__(256) void lu_all(float* __restrict__ A, unsigned* __restrict__ bar){
  __shared__ float shA[64 * 68];
  __shared__ float shB[64 * 68];
  int b = blockIdx.x, bi = b / 9, bj = b % 9;
  int t = threadIdx.x;
  unsigned seq = 0;

  for (int k = 0; k < 9; ++k){
    int k0 = k * 64;
    // ---------- phase D: diagonal factorization ----------
    if (bi == k && bj == k){
      for (int fid = t; fid < 1024; fid += 256){
        int row = fid >> 4, c4 = (fid & 15) << 2;
        float4 v = *(const float4*)&A[(size_t)(k0 + row) * NDP + k0 + c4];
        shA[row * 65 + c4 + 0] = v.x; shA[row * 65 + c4 + 1] = v.y;
        shA[row * 65 + c4 + 2] = v.z; shA[row * 65 + c4 + 3] = v.w;
      }
      __syncthreads();
      if (t < 64){
        int l = t;
        float r[64];
        #pragma unroll
        for (int c = 0; c < 64; ++c) r[c] = shA[l * 65 + c];
        #pragma unroll
        for (int j = 0; j < 64; ++j){
          float piv = __shfl(r[j], j);
          float lij = r[j] / piv;
          float m = (l > j) ? 1.f : 0.f;
          float mlij = m * lij;
          #pragma unroll
          for (int c = j + 1; c < 64; ++c){
            float rjc = __shfl(r[c], j);
            r[c] -= mlij * rjc;
          }
          if (l > j) r[j] = lij;
        }
        #pragma unroll
        for (int c = 0; c < 64; ++c) shA[l * 65 + c] = r[c];
      }
      __syncthreads();
      for (int fid = t; fid < 1024; fid += 256){
        int row = fid >> 4, c4 = (fid & 15) << 2;
        float4 v;
        v.x = shA[row * 65 + c4 + 0]; v.y = shA[row * 65 + c4 + 1];
        v.z = shA[row * 65 + c4 + 2]; v.w = shA[row * 65 + c4 + 3];
        *(float4*)&A[(size_t)(k0 + row) * NDP + k0 + c4] = v;
      }
    }
    grid_bar(bar, 81u * (++seq));
    if (k == 8) break;

    // ---------- phase T: panel TRSMs ----------
    bool uRole = (bi == k && bj > k);
    bool lRole = (bj == k && bi > k);
    if (uRole || lRole){
      int c0 = (uRole ? bj : bi) * 64;
      int rbase = uRole ? k0 : c0;
      int cbase = uRole ? c0 : k0;
      for (int fid = t; fid < 1024; fid += 256){
        int row = fid >> 4, c4 = (fid & 15) << 2;
        float4 v = *(const float4*)&A[(size_t)(k0 + row) * NDP + k0 + c4];
        shA[row * 65 + c4 + 0] = v.x; shA[row * 65 + c4 + 1] = v.y;
        shA[row * 65 + c4 + 2] = v.z; shA[row * 65 + c4 + 3] = v.w;
      }
      for (int fid = t; fid < 1024; fid += 256){
        int row = fid >> 4, c4 = (fid & 15) << 2;
        float4 v = *(const float4*)&A[(size_t)(rbase + row) * NDP + cbase + c4];
        shB[row * 65 + c4 + 0] = v.x; shB[row * 65 + c4 + 1] = v.y;
        shB[row * 65 + c4 + 2] = v.z; shB[row * 65 + c4 + 3] = v.w;
      }
      __syncthreads();
      if (t < 64){
        if (uRole){
          float x[64];
          #pragma unroll
          for (int i = 0; i < 64; ++i) x[i] = shB[i * 65 + t];
          #pragma unroll
          for (int i = 0; i < 64; ++i){
            #pragma unroll
            for (int ii = i + 1; ii < 64; ++ii)
              x[ii] -= shA[ii * 65 + i] * x[i];
          }
          #pragma unroll
          for (int i = 0; i < 64; ++i) shB[i * 65 + t] = x[i];
        } else {
          float x[64];
          #pragma unroll
          for (int j = 0; j < 64; ++j) x[j] = shB[t * 65 + j];
          #pragma unroll
          for (int j = 0; j < 64; ++j){
            x[j] /= shA[j * 65 + j];
            #pragma unroll
            for (int jj = j + 1; jj < 64; ++jj)
              x[jj] -= x[j] * shA[j * 65 + jj];
          }
          #pragma unroll
          for (int j = 0; j < 64; ++j) shB[t * 65 + j] = x[j];
        }
      }
      __syncthreads();
      for (int fid = t; fid < 1024; fid += 256){
        int row = fid >> 4, c4 = (fid & 15) << 2;
        float4 v;
        v.x = shB[row * 65 + c4 + 0]; v.y = shB[row * 65 + c4 + 1];
        v.z = shB[row * 65 + c4 + 2]; v.w = shB[row * 65 + c4 + 3];
        *(float4*)&A[(size_t)(rbase + row) * NDP + cbase + c4] = v;
      }
    }
    grid_bar(bar, 81u * (++seq));

    // ---------- phase G: trailing update ----------
    if (bi > k && bj > k){
      // stage L(bi,k) transposed (Lt[kk][i]) and U(k,bj) straight (Ut[kk][j]); stride 68
      {
        int i = t & 63, kkg = (t >> 6) * 16;
        const float* src = &A[(size_t)(bi * 64 + i) * NDP + k0 + kkg];
        float4 v0 = *(const float4*)(src + 0);
        float4 v1 = *(const float4*)(src + 4);
        float4 v2 = *(const float4*)(src + 8);
        float4 v3 = *(const float4*)(src + 12);
        float vv[16] = {v0.x,v0.y,v0.z,v0.w, v1.x,v1.y,v1.z,v1.w,
                        v2.x,v2.y,v2.z,v2.w, v3.x,v3.y,v3.z,v3.w};
        #pragma unroll
        for (int j = 0; j < 16; ++j) shA[(kkg + j) * 68 + i] = vv[j];
      }
      {
        int kk = t >> 2, j4 = (t & 3) * 16;
        const float* src = &A[(size_t)(k0 + kk) * NDP + bj * 64 + j4];
        float4 v0 = *(const float4*)(src + 0);
        float4 v1 = *(const float4*)(src + 4);
        float4 v2 = *(const float4*)(src + 8);
        float4 v3 = *(const float4*)(src + 12);
        *(float4*)&shB[kk * 68 + j4 + 0]  = v0;
        *(float4*)&shB[kk * 68 + j4 + 4]  = v1;
        *(float4*)&shB[kk * 68 + j4 + 8]  = v2;
        *(float4*)&shB[kk * 68 + j4 + 12] = v3;
      }
      __syncthreads();
      int i0t = (t >> 4) * 4, j0t = (t & 15) * 4;
      float acc[4][4];
      #pragma unroll
      for (int a = 0; a < 4; ++a)
        #pragma unroll
        for (int c = 0; c < 4; ++c) acc[a][c] = 0.f;
      for (int kk = 0; kk < 64; ++kk){
        float4 lv = *(const float4*)&shA[kk * 68 + i0t];
        float4 uv = *(const float4*)&shB[kk * 68 + j0t];
        float lvv[4] = {lv.x, lv.y, lv.z, lv.w};
        float uvv[4] = {uv.x, uv.y, uv.z, uv.w};
        #pragma unroll
        for (int a = 0; a < 4; ++a)
          #pragma unroll
          for (int c = 0; c < 4; ++c) acc[a][c] += lvv[a] * uvv[c];
      }
      __syncthreads();   // done reading shA/shB before next panel reuses them
      #pragma unroll
      for (int a = 0; a < 4; ++a){
        float* dst = &A[(size_t)(bi * 64 + i0t + a) * NDP + bj * 64 + j0t];
        float4 old = *(const float4*)dst;
        old.x -= acc[a][0]; old.y -= acc[a][1]; old.z -= acc[a][2]; old.w -= acc[a][3];
        *(float4*)dst = old;
      }
    }
    grid_bar(bar, 81u * (++seq));
  }
}

// ---- Parallel solve: 576 threads, thread i owns row i ----
__global__ __launch_bounds__(576) void solve_ll(
    const float* __restrict__ A, const float* __restrict__ r,
    float* __restrict__ tmp, float* __restrict__ out0){
  __shared__ float ys[NDP];
  __shared__ float red[16];
  int t = threadIdx.x;
  int w = t >> 6, l = t & 63;
  int i = t;
  float y = r[i];
  float rsave = y;
  float ldpart = 0.f;
  float row[64];

  for (int jb = 0; jb < 9; ++jb){
    if (w >= jb){
      const float4* ap = (const float4*)(A + (size_t)i * NDP + jb * 64);
      #pragma unroll
      for (int q = 0; q < 16; ++q) ((float4*)row)[q] = ap[q];
    }
    if (w == jb){
      #pragma unroll
      for (int j = 0; j < 64; ++j){
        float yj = __shfl(y, j);
        if (l > j) y -= row[j] * yj;
      }
      ys[i] = y;
    }
    __syncthreads();
    if (w > jb){
      #pragma unroll
      for (int j = 0; j < 64; ++j) y -= row[j] * ys[jb * 64 + j];
    }
  }
  __syncthreads();

  for (int jb = 8; jb >= 0; --jb){
    if (w <= jb){
      const float4* ap = (const float4*)(A + (size_t)i * NDP + jb * 64);
      #pragma unroll
      for (int q = 0; q < 16; ++q) ((float4*)row)[q] = ap[q];
    }
    if (w == jb){
      float dv = A[(size_t)i * NDP + i];
      float dinv = 1.f / dv;
      ldpart = logf(fabsf(dv));
      #pragma unroll
      for (int j = 63; j >= 0; --j){
        float yj = __shfl(y, j) * __shfl(dinv, j);
        if (l == j) y = yj;
        if (l < j)  y -= row[j] * yj;
      }
      ys[i] = y;
    }
    __syncthreads();
    if (w < jb){
      #pragma unroll
      for (int j = 0; j < 64; ++j) y -= row[j] * ys[jb * 64 + j];
    }
  }

  tmp[i] = y;
  float contrib = ldpart + rsave * y;
  #pragma unroll
  for (int off = 32; off; off >>= 1) contrib += __shfl_down(contrib, off);
  if (l == 0) red[w] = contrib;
  __syncthreads();
  if (t == 0){
    float s = 0.f;
    #pragma unroll
    for (int k = 0; k < 9; ++k) s += red[k];
    out0[0] = s;
  }
}

// ---- m_posterior = m0 + P @ tmp ----
__global__ void mpost(const float* __restrict__ P, const float* __restrict__ tmp,
                      const float* __restrict__ m0p, float* __restrict__ out1){
  int w = threadIdx.x >> 6, l = threadIdx.x & 63;
  int m = blockIdx.x * 4 + w;
  if (m >= NM) return;
  float s = 0.f;
  #pragma unroll
  for (int i = 0; i < 9; ++i){
    int n = i * 64 + l;
    s += P[(size_t)m * NDP + n] * tmp[n];
  }
  #pragma unroll
  for (int off = 32; off; off >>= 1) s += __shfl_down(s, off);
  if (l == 0) out1[m] = m0p[0] + s;
}

extern "C" void kernel_launch(void* const* d_in, const int* in_sizes, int n_in,
                              void* d_out, int out_size, void* d_ws, size_t ws_size,
                              hipStream_t stream){
  const float* dist = (const float*)d_in[0];
  const float* F    = (const float*)d_in[1];
  const float* dobs = (const float*)d_in[2];
  const float* dcov = (const float*)d_in[3];
  const float* m0p  = (const float*)d_in[4];
  const float* lsp  = (const float*)d_in[5];
  const float* sgp  = (const float*)d_in[6];
  float* out = (float*)d_out;
  char* ws = (char*)d_ws;

  unsigned short* Bt = (unsigned short*)(ws + 0);
  float*          P  = (float*)(ws + 11538432);
  unsigned short* Pb = (unsigned short*)(ws + 34578432);
  float*          A  = (float*)(ws + 46116864);
  float*          r  = (float*)(ws + 47443968);
  float*          tp = (float*)(ws + 47446272);
  unsigned*       bar= (unsigned*)(ws + 47448576);

  hipMemsetAsync(P, 0, (size_t)NM * NDP * sizeof(float), stream);
  prep_bt<<<NKB * 9, 256, 0, stream>>>(F, Bt);
  rvec<<<NDP, 256, 0, stream>>>(F, dobs, m0p, r);
  gemm1<<<MT64 * SPLITK, 384, 0, stream>>>(dist, Bt, P, lsp, sgp);
  conv_p<<<NKB * 9, 256, 0, stream>>>(P, Pb);
  a_init<<<(NDP * NDP + 255) / 256, 256, 0, stream>>>(dcov, A, bar);
  gemm2<<<81 * 3, 256, 0, stream>>>(Bt, Pb, A);
  lu_all<<<81, 256, 0, stream>>>(A, bar);
  solve_ll<<<1, 576, 0, stream>>>(A, r, tp, out);
  mpost<<<2500, 256, 0, stream>>>(P, tp, m0p, out + 1);
}